// Round 16
// baseline (927.759 us; speedup 1.0000x reference)
//
#include <hip/hip_runtime.h>

// DegModel: kernel-prediction net (17x conv3x3 + 1x1 conv to 441 taps) +
// tap-normalized spatially-varying 21x21 downsample (stride 4, reflect pad).
//
// fp64 conv chain (1/tap-sum amplification: fp32 chain fails 1280 > 1177;
// fp64 passes at 576). Round 21:
//  - conv3x3 (CIN=64): DEPTH-4 B-PREFETCH, window bW[6][2], slot=t%6,
//    18-step unroll (2 ch-groups; 18%6==18%3... both compile-time).
//    r14 counters: MfmaUtil 47, VALU 9 -> 44% no-issue = B latency
//    (depth-2 lead 512cy < L3 600-900cy; FETCH 18.4MB = hp crosses
//    fabric every dispatch). Depth-4 lead = 1024cy > latency. Main loop
//    (7/8 iters) has ZERO guards (fewer branches than 44us baseline);
//    last iter peeled with compile-time guards. A stays 3-slot depth-2
//    (L2-resident, covered). +12 VGPR, fits LB(256,2). CIN=3 keeps the
//    old verified path. r16's depth-3 failure was impl bloat (runtime
//    selects); r19's occupancy failure duplicated B — this does neither.
//  - apply: r20 rewrite verified (55->53.5us, WRITE 58->0.4MB); parked
//    (VGPR=12 latency-bound, ~20us upside).
//  - lastconv: tap-group + 4x grid + fused normalization (verified).
//  - sums_kernel stores inv = 1/(s+1e-8); apply read-only on kout.
// On-device layout probe (r8 lesson: assumed f64 MFMA maps were wrong).

#define NB 8        // batch
#define NF 64       // features
#define SP 4096     // 64*64 spatial
#define PS 66       // padded spatial dim
#define PS2 4356    // 66*66
#define K2 441      // 21*21 taps
#define K2P 448     // padded taps
#define RES_WSTRIDE (64*64*9)
// packed-K fragment sizes: NS(CIN) = ceil(CIN*9/4) steps, 4 mt-tiles, 64 lanes
#define WF_RES 36864           // 144 steps * 256
#define WF_C0  1792            // 7 steps * 256
#define WTA_N  28672           // 16kk * 28mt * 64

typedef double vdbl4 __attribute__((ext_vector_type(4)));

// table offsets (ints) within the tabs block
#define T_AI 0      // [64]  A: lane -> i
#define T_AK 64     // [64]  A: lane -> k
#define T_BK 128    // [64]  B: lane -> k
#define T_BJ 192    // [64]  B: lane -> j
#define T_DI 256    // [256] D: r*64+l -> i
#define T_DJ 512    // [256] D: r*64+l -> j

// ---------------------------------------------------------------------------
// layout probe: one wave. D1[l,r] = rowsumA(i(l,r)), D2[l,r] = colsumB(j(l,r))
__global__ void probe_mfma(double* __restrict__ probe)
{
    int l = threadIdx.x;
    vdbl4 z = {0.0, 0.0, 0.0, 0.0};
    vdbl4 r1 = __builtin_amdgcn_mfma_f64_16x16x4f64((double)l, 1.0, z, 0, 0, 0);
    vdbl4 r2 = __builtin_amdgcn_mfma_f64_16x16x4f64(1.0, (double)l, z, 0, 0, 0);
#pragma unroll
    for (int r = 0; r < 4; ++r) {
        probe[r * 64 + l]       = r1[r];
        probe[256 + r * 64 + l] = r2[r];
    }
}

__global__ void decode_probe(const double* __restrict__ probe, int* __restrict__ tabs)
{
    int t = threadIdx.x;                 // 0..255
    const double* d1 = probe;
    const double* d2 = probe + 256;
    // lane=i+16k => rowsum=96+4i (mod4==0); lane=4i+k => 6+16i (mod4==2)
    bool fA = ((((int)d1[0]) & 3) == 0);
    bool fB = ((((int)d2[0]) & 3) == 0);
    int v1 = (int)d1[t], v2 = (int)d2[t];
    tabs[T_DI + t] = fA ? (v1 - 96) >> 2 : (v1 - 6) >> 4;
    tabs[T_DJ + t] = fB ? (v2 - 96) >> 2 : (v2 - 6) >> 4;
    if (t < 64) {
        tabs[T_AI + t] = fA ? (t & 15) : (t >> 2);
        tabs[T_AK + t] = fA ? (t >> 4) : (t & 3);
        tabs[T_BK + t] = fB ? (t >> 4) : (t & 3);
        tabs[T_BJ + t] = fB ? (t & 15) : (t >> 2);
    }
}

// ---------------------------------------------------------------------------
// z (8,3,64,64) fp32 -> zp (8,3,66,66) fp64 interior (borders pre-zeroed)
__global__ void prep_zpad(const float* __restrict__ z, double* __restrict__ zp)
{
    int i = blockIdx.x * blockDim.x + threadIdx.x;
    if (i >= NB * 3 * SP) return;
    int bc = i >> 12, p = i & 4095, y = p >> 6, x = p & 63;
    zp[(size_t)(bc * PS + y + 1) * PS + x + 1] = (double)z[i];
}

// conv weights OIHW fp32 -> packed-K MFMA A-fragment order (table-driven).
// WF[t][mt][lane] = W[oc = mt*16+Ai(l)][c = kg/9][tap = kg%9], kg = t*4+Ak(l);
// kg >= CIN*9 -> 0 (pad, CIN=3 tail only).
__global__ void prep_convw_frag(const float* __restrict__ src, double* __restrict__ dst,
                                const int* __restrict__ tabs,
                                int CIN, int nlayer, int wstride)
{
    int i = blockIdx.x * blockDim.x + threadIdx.x;
    int NS = (CIN * 9 + 3) / 4;
    int M  = NS * 256;
    if (i >= nlayer * M) return;
    int li  = i / M;
    int rem = i - li * M;
    int t   = rem >> 8;
    int j   = rem & 255;
    int mt  = j >> 6;
    int l   = j & 63;
    int kg  = t * 4 + tabs[T_AK + l];
    int oc  = mt * 16 + tabs[T_AI + l];
    int c   = kg / 9;
    int tap = kg - c * 9;
    dst[i] = (kg < CIN * 9) ? (double)src[li * wstride + (oc * CIN + c) * 9 + tap] : 0.0;
}

// bias fp32 -> C-fragment order fp64
__global__ void prep_bias_frag(const float* __restrict__ src, double* __restrict__ dst,
                               const int* __restrict__ tabs, int nlayer)
{
    int i = blockIdx.x * blockDim.x + threadIdx.x;
    if (i >= nlayer * 1024) return;
    int li  = i >> 10;
    int j   = i & 1023;
    int mtr = j >> 6;
    int l   = j & 63;
    int mt  = mtr >> 2, r = mtr & 3;
    dst[i] = (double)src[li * 64 + mt * 16 + tabs[T_DI + r * 64 + l]];
}

// last_w (441,64) -> A-fragment order WtA[kk][mt][lane] =
// W[tap = mt*16+Ai(l)][c = kk*4+Ak(l)] (tap>=441 -> 0); lbp padded bias.
__global__ void prep_lastwa(const float* __restrict__ lw, const float* __restrict__ lb,
                            const int* __restrict__ tabs,
                            double* __restrict__ wta, double* __restrict__ lbp)
{
    int i = blockIdx.x * blockDim.x + threadIdx.x;
    if (i < WTA_N) {
        int kk = i / (28 * 64);
        int rem = i - kk * (28 * 64);
        int mt = rem >> 6;
        int l  = rem & 63;
        int c  = kk * 4 + tabs[T_AK + l];
        int T  = mt * 16 + tabs[T_AI + l];
        wta[i] = (T < K2) ? (double)lw[T * 64 + c] : 0.0;
    }
    if (i < K2P) lbp[i] = (i < K2) ? (double)lb[i] : 0.0;
}

// wsum[c] = sum_T lw[T][c] (fp64, T-ascending); wsum[64] = sum_T lb[T]
__global__ void prep_wsum(const float* __restrict__ lw, const float* __restrict__ lb,
                          double* __restrict__ wsum)
{
    int c = threadIdx.x;
    if (c < 64) {
        double s = 0.0;
        for (int t = 0; t < K2; ++t) s += (double)lw[t * 64 + c];
        wsum[c] = s;
    }
    if (c == 64) {
        double s = 0.0;
        for (int t = 0; t < K2; ++t) s += (double)lb[t];
        wsum[64] = s;
    }
}

// ---------------------------------------------------------------------------
// conv3x3 as packed-K fp64 MFMA GEMM: D(64oc x 64pos) = WF(64 x CIN*9) * P.
// Channels in groups of 4: 36 taps = 9 exact K=4 steps (no pad for CIN=64).
// CIN=64 path: depth-4 B window bW[6][2] (slot t%6), 18-step unroll,
// guard-free main loop + peeled last iter. A: 3-slot depth-2 (t%3).
// CIN=3 path: r12-verified depth-2. Grid 512, 2 blocks/CU.
// ---------------------------------------------------------------------------
template<int CIN, bool RELU, bool RESADD>
__global__ __launch_bounds__(256, 2)
void conv3x3_mfma(const double* __restrict__ in, const double* __restrict__ WF,
                  const double* __restrict__ BF, const int* __restrict__ tabs,
                  const double* __restrict__ res, double* __restrict__ out)
{
    constexpr int KT = CIN * 9;          // real K
    constexpr int NS = (KT + 3) / 4;     // K=4 steps (64ch: 144, 3ch: 7)
    constexpr int G  = (NS + 8) / 9;     // 4-channel groups

    const int bid = blockIdx.x;
    const int b   = bid & 7;
    const int y0  = bid >> 3;          // output row 0..63
    const int tid = threadIdx.x;
    const int w   = tid >> 6;
    const int l   = tid & 63;
    const int mi  = w >> 1, ni = w & 1;
    const int mt0 = mi * 2, nt0 = ni * 2;

    const int kB = tabs[T_BK + l];
    const int jB = tabs[T_BJ + l];

    // per-lane B offsets for the 9 steps of a 4-channel group.
    // kg = s*4 + kB in 0..35 -> c = kg/9, tap = kg%9. Pad slot (CIN=3 tail,
    // kg >= KT < 36) aliases addr 0 within the plane; weight there is 0.
    int offp[9];
#pragma unroll
    for (int s = 0; s < 9; ++s) {
        int kg  = s * 4 + kB;
        int off = 0;
        if (KT >= 36 || kg < KT) {
            int c   = kg / 9;
            int tap = kg - c * 9;
            int dy  = tap / 3, dx = tap - dy * 3;
            off = c * PS2 + dy * PS + dx;
        }
        offp[s] = off + jB + nt0 * 16;
    }

    const double* bbase = in + (size_t)b * CIN * PS2 + (size_t)y0 * PS;

    vdbl4 acc[2][2];
#pragma unroll
    for (int mt = 0; mt < 2; ++mt)
#pragma unroll
        for (int r = 0; r < 4; ++r) {
            double bv = BF[((mt0 + mt) * 4 + r) * 64 + l];
            acc[mt][0][r] = bv;
            acc[mt][1][r] = bv;
        }

    if constexpr (KT >= 36) {
        // CIN=64: NS = 144 = 8 x 18. Depth-4 B window, compile-time slots.
        static_assert(NS % 18 == 0, "18-step unroll requires NS % 18 == 0");
        double aS[3][2], bW[6][2];
        auto ldA = [&](int t, int slot) {
            const double* p = WF + (size_t)t * 256 + l;
            aS[slot][0] = p[mt0 * 64];
            aS[slot][1] = p[(mt0 + 1) * 64];
        };
        auto ldB = [&](int slot, size_t cgoff, int s9) {
            const double* p = bbase + cgoff + offp[s9];
            bW[slot][0] = p[0];
            bW[slot][1] = p[16];
        };
        auto step = [&](int as, int bs) {
            acc[0][0] = __builtin_amdgcn_mfma_f64_16x16x4f64(aS[as][0], bW[bs][0], acc[0][0], 0, 0, 0);
            acc[0][1] = __builtin_amdgcn_mfma_f64_16x16x4f64(aS[as][0], bW[bs][1], acc[0][1], 0, 0, 0);
            acc[1][0] = __builtin_amdgcn_mfma_f64_16x16x4f64(aS[as][1], bW[bs][0], acc[1][0], 0, 0, 0);
            acc[1][1] = __builtin_amdgcn_mfma_f64_16x16x4f64(aS[as][1], bW[bs][1], acc[1][1], 0, 0, 0);
        };

        // prologue: B for steps 0..3 (all in group 0; 3 < 9), A for 0,1
        ldB(0, 0, 0); ldB(1, 0, 1); ldB(2, 0, 2); ldB(3, 0, 3);
        ldA(0, 0); ldA(1, 1);

        constexpr int NIT = NS / 18;     // 8
        for (int it = 0; it < NIT - 1; ++it) {
            const size_t cgb = (size_t)it * 8 * PS2;   // 2 groups x 4ch per iter
#pragma unroll
            for (int s18 = 0; s18 < 18; ++s18) {
                // guard-free: for it <= NIT-2, t+4 <= NS-15 and t+2 <= NS-17
                ldB((s18 + 4) % 6, cgb + (size_t)((s18 + 4) / 9) * 4 * PS2, (s18 + 4) % 9);
                ldA(it * 18 + s18 + 2, (s18 + 2) % 3);
                step(s18 % 3, s18 % 6);
            }
        }
        {   // peeled last iter: compile-time guards
            const int it = NIT - 1;
            const size_t cgb = (size_t)it * 8 * PS2;
#pragma unroll
            for (int s18 = 0; s18 < 18; ++s18) {
                if (s18 + 4 < 18)
                    ldB((s18 + 4) % 6, cgb + (size_t)((s18 + 4) / 9) * 4 * PS2, (s18 + 4) % 9);
                if (s18 + 2 < 18)
                    ldA(it * 18 + s18 + 2, (s18 + 2) % 3);
                step(s18 % 3, s18 % 6);
            }
        }
    } else {
        // CIN=3: r12-verified depth-2 path (NS=7, G=1, tail break)
        double aS[3][2], bS[3][2];
        auto ldA = [&](int t, int slot) {
            const double* p = WF + (size_t)t * 256 + l;
            aS[slot][0] = p[mt0 * 64];
            aS[slot][1] = p[(mt0 + 1) * 64];
        };
        auto ldB = [&](size_t cg, int s, int slot) {
            const double* p = bbase + cg + offp[s];
            bS[slot][0] = p[0];
            bS[slot][1] = p[16];
        };
        auto step = [&](int slot) {
            acc[0][0] = __builtin_amdgcn_mfma_f64_16x16x4f64(aS[slot][0], bS[slot][0], acc[0][0], 0, 0, 0);
            acc[0][1] = __builtin_amdgcn_mfma_f64_16x16x4f64(aS[slot][0], bS[slot][1], acc[0][1], 0, 0, 0);
            acc[1][0] = __builtin_amdgcn_mfma_f64_16x16x4f64(aS[slot][1], bS[slot][0], acc[1][0], 0, 0, 0);
            acc[1][1] = __builtin_amdgcn_mfma_f64_16x16x4f64(aS[slot][1], bS[slot][1], acc[1][1], 0, 0, 0);
        };

        ldA(0, 0); ldB(0, 0, 0);
        ldA(1, 1); ldB(0, 1, 1);

        for (int g = 0; g < G; ++g) {
            const size_t cg = (size_t)g * 4 * PS2;
#pragma unroll
            for (int s = 0; s < 9; ++s) {
                const int t = g * 9 + s;
                if (KT % 36 != 0 && t >= NS) break;
                const int tp = t + 2;
                if (tp < NS) {
                    const int    ps  = (s + 2 < 9) ? s + 2 : s - 7;
                    const size_t pcg = (s + 2 < 9) ? cg : cg + 4 * PS2;
                    ldA(tp, (s + 2) % 3);
                    ldB(pcg, ps, (s + 2) % 3);
                }
                step(s % 3);
            }
        }
    }

    // epilogue: D element (i,j) per (lane, reg) from probe tables
    int iD[4], jD[4];
#pragma unroll
    for (int r = 0; r < 4; ++r) {
        iD[r] = tabs[T_DI + r * 64 + l];
        jD[r] = tabs[T_DJ + r * 64 + l];
    }
#pragma unroll
    for (int mt = 0; mt < 2; ++mt)
#pragma unroll
        for (int nt = 0; nt < 2; ++nt)
#pragma unroll
            for (int r = 0; r < 4; ++r) {
                int oc = (mt0 + mt) * 16 + iD[r];
                int x  = (nt0 + nt) * 16 + jD[r];
                size_t idx = (size_t)(b * NF + oc) * PS2 + (size_t)(y0 + 1) * PS + x + 1;
                double val = acc[mt][nt][r];
                if (RELU)   val = fmax(val, 0.0);
                if (RESADD) val += res[idx];
                out[idx] = val;
            }
}

// ---------------------------------------------------------------------------
// 1x1 conv as fp64 MFMA GEMM, taps-as-M, TAP-GROUP blocks (r14 traffic fix,
// r15 4x grid: 1792 blocks) + FUSED tap-normalization (r16 verified:
// apply WRITE 58->1.5 MB): stores (float)(acc_f64 * inv_f64), inv from
// sums_kernel. Wave w owns mt = tg*4+w (16 tap rows) x 128 contiguous pos;
// A preloaded in 16 VGPRs; acc[4] indep MFMA chains; stores 16 taps x
// 256 B contiguous runs. No LDS.
// ---------------------------------------------------------------------------
__global__ __launch_bounds__(256, 2)
void lastconv_mfma(const double* __restrict__ hp, const double* __restrict__ wta,
                   const double* __restrict__ lbp, const int* __restrict__ tabs,
                   const double* __restrict__ inv_sums, float* __restrict__ kraw)
{
    const int bid = blockIdx.x;
    const int b   = bid / 224;
    const int rem = bid - b * 224;
    const int tg  = rem >> 5;          // 0..6
    const int pc  = rem & 31;          // 0..31
    const int tid = threadIdx.x;
    const int w   = tid >> 6;
    const int l   = tid & 63;
    const int mt  = tg * 4 + w;        // 0..27

    const int kB = tabs[T_BK + l];
    const int jB = tabs[T_BJ + l];
    int iD[4], jD[4];
#pragma unroll
    for (int r = 0; r < 4; ++r) {
        iD[r] = tabs[T_DI + r * 64 + l];
        jD[r] = tabs[T_DJ + r * 64 + l];
    }

    // preload A fragments for this mt: 16 doubles/lane
    double avs[16];
#pragma unroll
    for (int kk = 0; kk < 16; ++kk)
        avs[kk] = wta[((size_t)kk * 28 + mt) * 64 + l];

    // bias per accumulator register (same for all j-tiles)
    double bias[4];
#pragma unroll
    for (int r = 0; r < 4; ++r)
        bias[r] = lbp[mt * 16 + iD[r]];

    const double* hb = hp + (size_t)b * NF * PS2;
    float* kb = kraw + (size_t)b * K2 * SP;

    for (int q = 0; q < 2; ++q) {
        const int P0  = pc * 128 + q * 64;   // 64 positions = one spatial row
        const int row = P0 >> 6;
        const double* hrow = hb + (size_t)(row + 1) * PS + 1 + jB;

        // inv at this lane's 16 store positions (hidden under the K-loop)
        const double* isrow = inv_sums + (size_t)b * SP + P0;
        double isv[4][4];
#pragma unroll
        for (int j = 0; j < 4; ++j)
#pragma unroll
            for (int r = 0; r < 4; ++r)
                isv[j][r] = isrow[j * 16 + jD[r]];

        vdbl4 acc[4];
#pragma unroll
        for (int j = 0; j < 4; ++j)
#pragma unroll
            for (int r = 0; r < 4; ++r)
                acc[j][r] = bias[r];

        // prefetch B for kk=0 (c = kB)
        double bc[4], bn[4];
#pragma unroll
        for (int j = 0; j < 4; ++j)
            bc[j] = hrow[(size_t)kB * PS2 + j * 16];

        for (int kk = 0; kk < 16; ++kk) {
            if (kk < 15) {
                const double* np = hrow + (size_t)((kk + 1) * 4 + kB) * PS2;
#pragma unroll
                for (int j = 0; j < 4; ++j) bn[j] = np[j * 16];
            }
#pragma unroll
            for (int j = 0; j < 4; ++j)
                acc[j] = __builtin_amdgcn_mfma_f64_16x16x4f64(avs[kk], bc[j], acc[j], 0, 0, 0);
#pragma unroll
            for (int j = 0; j < 4; ++j) bc[j] = bn[j];
        }

        // epilogue: normalized stores, 16 taps x 4 x 64 B contiguous runs
#pragma unroll
        for (int r = 0; r < 4; ++r) {
            int T = mt * 16 + iD[r];
            if (T < K2) {
                float* p = kb + (size_t)T * SP + P0;
                p[jD[r]]      = (float)(acc[0][r] * isv[0][r]);
                p[16 + jD[r]] = (float)(acc[1][r] * isv[1][r]);
                p[32 + jD[r]] = (float)(acc[2][r] * isv[2][r]);
                p[48 + jD[r]] = (float)(acc[3][r] * isv[3][r]);
            }
        }
    }
}

// ---------------------------------------------------------------------------
// inv_sums[b][p] = 1 / (sum_c hp[c,p] * wsum[c] + wsum[64] + 1e-8)
// (exact refactoring of the tap-sum; fp64 reassociation ~1e-15 rel)
// ---------------------------------------------------------------------------
__global__ __launch_bounds__(256)
void sums_kernel(const double* __restrict__ hp, const double* __restrict__ wsum,
                 double* __restrict__ inv_sums)
{
    int i = blockIdx.x * 256 + threadIdx.x;   // 0..32767
    int b = i >> 12, p = i & 4095;
    int y = p >> 6, x = p & 63;
    const double* hb = hp + (size_t)b * NF * PS2 + (size_t)(y + 1) * PS + 1 + x;
    double s = wsum[64];
    for (int c = 0; c < 64; ++c) s += hb[(size_t)c * PS2] * wsum[c];
    inv_sums[b * SP + p] = 1.0 / (s + 1e-8);
}

// ---------------------------------------------------------------------------
// Apply normalized kernel (kout already normalized by lastconv) to
// reflect-padded 21x21 patches of x. r20 rewrite (verified): no x-LDS
// staging, no atomics. Block = (b, row): 64 px x 4 tap-chunks; kout reads
// 256B-coalesced; x via L1; 3KB LDS 4-way reduce; plain stores.
// ---------------------------------------------------------------------------
__global__ __launch_bounds__(256)
void apply_kernel(const float* __restrict__ x, const float* __restrict__ kout,
                  float* __restrict__ out)
{
    const int bid   = blockIdx.x;
    const int b     = bid >> 6;
    const int row   = bid & 63;
    const int tid   = threadIdx.x;
    const int chunk = tid >> 6;        // 0..3
    const int px    = tid & 63;
    const int p     = row * 64 + px;

    const float* xb = x + (size_t)b * 3 * 65536;
    const float* kb = kout + (size_t)b * K2 * SP + p;

    float o0 = 0.f, o1 = 0.f, o2 = 0.f;
    const int t0 = chunk * 111;
    const int t1 = (t0 + 111 < K2) ? t0 + 111 : K2;
    for (int t = t0; t < t1; ++t) {
        int ty = t / 21, tx = t - ty * 21;
        float kn = kb[(size_t)t * SP];
        int gr = row * 4 + ty - 10;
        int gc = px * 4 + tx - 10;
        gr = gr < 0 ? -gr : (gr > 255 ? 510 - gr : gr);
        gc = gc < 0 ? -gc : (gc > 255 ? 510 - gc : gc);
        const float* xp = xb + gr * 256 + gc;
        o0 = fmaf(xp[0],       kn, o0);
        o1 = fmaf(xp[65536],   kn, o1);
        o2 = fmaf(xp[131072],  kn, o2);
    }

    __shared__ float red[3][4][64];
    if (chunk > 0) {
        red[0][chunk][px] = o0;
        red[1][chunk][px] = o1;
        red[2][chunk][px] = o2;
    }
    __syncthreads();
    if (chunk == 0) {
        o0 += red[0][1][px] + red[0][2][px] + red[0][3][px];
        o1 += red[1][1][px] + red[1][2][px] + red[1][3][px];
        o2 += red[2][1][px] + red[2][2][px] + red[2][3][px];
        out[(b * 3 + 0) * SP + p] = o0;
        out[(b * 3 + 1) * SP + p] = o1;
        out[(b * 3 + 2) * SP + p] = o2;
    }
}

// ---------------------------------------------------------------------------
extern "C" void kernel_launch(void* const* d_in, const int* in_sizes, int n_in,
                              void* d_out, int out_size, void* d_ws, size_t ws_size,
                              hipStream_t stream)
{
    (void)in_sizes; (void)n_in; (void)out_size; (void)ws_size;

    const float* x = (const float*)d_in[0];
    const float* z = (const float*)d_in[1];

    float* out  = (float*)d_out;                 // (8,3,64,64)
    float* kout = (float*)d_out + NB * 3 * SP;   // (8,441,64,64) normalized

    // ws layout (doubles)
    double* wd    = (double*)d_ws;
    double* probe = wd;                      // 512 (D1, D2)
    int*    tabs  = (int*)(wd + 512);        // 1024 ints (=512 doubles)
    double* wf0   = wd + 1024;               // 1792
    double* wf1   = wf0 + WF_C0;             // 8*36864
    double* wf2   = wf1 + 8 * WF_RES;        // 8*36864
    double* bf0   = wf2 + 8 * WF_RES;        // 1024
    double* bf1   = bf0 + 1024;              // 8*1024
    double* bf2   = bf1 + 8 * 1024;          // 8*1024
    double* wta   = bf2 + 8 * 1024;          // 28672
    double* lbp   = wta + WTA_N;             // 448
    double* wsum  = lbp + K2P;               // 72
    double* zp    = wsum + 72;               // 8*3*66*66
    double* hp    = zp + NB * 3 * PS2;       // 8*64*66*66 = 17.8 MB
    double* tp    = hp + NB * NF * PS2;      // 17.8 MB
    double* sums  = tp;                      // aliases tp (free after conv chain)

    // zero padded buffers (borders must be 0; interiors get overwritten)
    hipMemsetAsync(zp, 0, (size_t)NB * 3 * PS2 * sizeof(double), stream);
    hipMemsetAsync(hp, 0, (size_t)NB * NF * PS2 * sizeof(double), stream);
    hipMemsetAsync(tp, 0, (size_t)NB * NF * PS2 * sizeof(double), stream);

    // layout probe, then table-driven prep
    probe_mfma<<<1, 64, 0, stream>>>(probe);
    decode_probe<<<1, 256, 0, stream>>>(probe, tabs);

    prep_zpad<<<(NB * 3 * SP + 255) / 256, 256, 0, stream>>>(z, zp);
    prep_convw_frag<<<(WF_C0 + 255) / 256, 256, 0, stream>>>(
        (const float*)d_in[2], wf0, tabs, 3, 1, 0);
    prep_convw_frag<<<(8 * WF_RES + 255) / 256, 256, 0, stream>>>(
        (const float*)d_in[4], wf1, tabs, 64, 8, RES_WSTRIDE);
    prep_convw_frag<<<(8 * WF_RES + 255) / 256, 256, 0, stream>>>(
        (const float*)d_in[6], wf2, tabs, 64, 8, RES_WSTRIDE);
    prep_bias_frag<<<(1024 + 255) / 256, 256, 0, stream>>>(
        (const float*)d_in[3], bf0, tabs, 1);
    prep_bias_frag<<<(8 * 1024 + 255) / 256, 256, 0, stream>>>(
        (const float*)d_in[5], bf1, tabs, 8);
    prep_bias_frag<<<(8 * 1024 + 255) / 256, 256, 0, stream>>>(
        (const float*)d_in[7], bf2, tabs, 8);
    prep_lastwa<<<(WTA_N + 255) / 256, 256, 0, stream>>>(
        (const float*)d_in[8], (const float*)d_in[9], tabs, wta, lbp);
    prep_wsum<<<1, 128, 0, stream>>>(
        (const float*)d_in[8], (const float*)d_in[9], wsum);

    conv3x3_mfma<3,  false, false><<<512, 256, 0, stream>>>(zp, wf0, bf0, tabs, nullptr, hp);
    for (int i = 0; i < 8; ++i) {
        conv3x3_mfma<64, true,  false><<<512, 256, 0, stream>>>(
            hp, wf1 + i * WF_RES, bf1 + i * 1024, tabs, nullptr, tp);
        conv3x3_mfma<64, false, true ><<<512, 256, 0, stream>>>(
            tp, wf2 + i * WF_RES, bf2 + i * 1024, tabs, hp, hp);
    }
    sums_kernel<<<128, 256, 0, stream>>>(hp, wsum, sums);
    lastconv_mfma<<<1792, 256, 0, stream>>>(hp, wta, lbp, tabs, sums, kout);
    apply_kernel<<<512, 256, 0, stream>>>(x, kout, out);
}

// Round 18
// 893.200 us; speedup vs baseline: 1.0387x; 1.0387x over previous
//
#include <hip/hip_runtime.h>

// DegModel: kernel-prediction net (17x conv3x3 + 1x1 conv to 441 taps) +
// tap-normalized spatially-varying 21x21 downsample (stride 4, reflect pad).
//
// fp64 conv chain (1/tap-sum amplification: fp32 chain fails 1280 > 1177;
// fp64 passes at 576). Round 22 (resubmit — GPU unavailable r17):
//  - conv3x3: depth-2 packed-K fp64 MFMA GEMM — FINAL. The prefetch ledger:
//    depth-3 (+90us), OC-split (+200us), depth-4 (+32us) ALL regressed vs
//    this 44 us/dispatch schedule. Conv is at a practical plateau (70% of
//    the 31 us MFMA floor); the stall is not coverable by deeper register
//    windows (suspect in-order VMEM return / icache). Do not touch again.
//  - apply_kernel: 4-WIDE UNROLLED gathers. r21 counters (stable x3 runs):
//    VGPR=12, 880 GB/s, Occ 19% -> compiler kept ~1 kout load in flight,
//    111 iters serialize on ~500cy latency. Explicit 4x unroll loads 4 kn
//    + 4 x-addresses before use (exact fp32 order preserved, bit-identical).
//  - lastconv: tap-group + 4x grid + fused normalization (verified).
//  - sums_kernel stores inv = 1/(s+1e-8); apply read-only on kout.
// On-device layout probe (r8 lesson: assumed f64 MFMA maps were wrong).

#define NB 8        // batch
#define NF 64       // features
#define SP 4096     // 64*64 spatial
#define PS 66       // padded spatial dim
#define PS2 4356    // 66*66
#define K2 441      // 21*21 taps
#define K2P 448     // padded taps
#define RES_WSTRIDE (64*64*9)
// packed-K fragment sizes: NS(CIN) = ceil(CIN*9/4) steps, 4 mt-tiles, 64 lanes
#define WF_RES 36864           // 144 steps * 256
#define WF_C0  1792            // 7 steps * 256
#define WTA_N  28672           // 16kk * 28mt * 64

typedef double vdbl4 __attribute__((ext_vector_type(4)));

// table offsets (ints) within the tabs block
#define T_AI 0      // [64]  A: lane -> i
#define T_AK 64     // [64]  A: lane -> k
#define T_BK 128    // [64]  B: lane -> k
#define T_BJ 192    // [64]  B: lane -> j
#define T_DI 256    // [256] D: r*64+l -> i
#define T_DJ 512    // [256] D: r*64+l -> j

// ---------------------------------------------------------------------------
// layout probe: one wave. D1[l,r] = rowsumA(i(l,r)), D2[l,r] = colsumB(j(l,r))
__global__ void probe_mfma(double* __restrict__ probe)
{
    int l = threadIdx.x;
    vdbl4 z = {0.0, 0.0, 0.0, 0.0};
    vdbl4 r1 = __builtin_amdgcn_mfma_f64_16x16x4f64((double)l, 1.0, z, 0, 0, 0);
    vdbl4 r2 = __builtin_amdgcn_mfma_f64_16x16x4f64(1.0, (double)l, z, 0, 0, 0);
#pragma unroll
    for (int r = 0; r < 4; ++r) {
        probe[r * 64 + l]       = r1[r];
        probe[256 + r * 64 + l] = r2[r];
    }
}

__global__ void decode_probe(const double* __restrict__ probe, int* __restrict__ tabs)
{
    int t = threadIdx.x;                 // 0..255
    const double* d1 = probe;
    const double* d2 = probe + 256;
    // lane=i+16k => rowsum=96+4i (mod4==0); lane=4i+k => 6+16i (mod4==2)
    bool fA = ((((int)d1[0]) & 3) == 0);
    bool fB = ((((int)d2[0]) & 3) == 0);
    int v1 = (int)d1[t], v2 = (int)d2[t];
    tabs[T_DI + t] = fA ? (v1 - 96) >> 2 : (v1 - 6) >> 4;
    tabs[T_DJ + t] = fB ? (v2 - 96) >> 2 : (v2 - 6) >> 4;
    if (t < 64) {
        tabs[T_AI + t] = fA ? (t & 15) : (t >> 2);
        tabs[T_AK + t] = fA ? (t >> 4) : (t & 3);
        tabs[T_BK + t] = fB ? (t >> 4) : (t & 3);
        tabs[T_BJ + t] = fB ? (t & 15) : (t >> 2);
    }
}

// ---------------------------------------------------------------------------
// z (8,3,64,64) fp32 -> zp (8,3,66,66) fp64 interior (borders pre-zeroed)
__global__ void prep_zpad(const float* __restrict__ z, double* __restrict__ zp)
{
    int i = blockIdx.x * blockDim.x + threadIdx.x;
    if (i >= NB * 3 * SP) return;
    int bc = i >> 12, p = i & 4095, y = p >> 6, x = p & 63;
    zp[(size_t)(bc * PS + y + 1) * PS + x + 1] = (double)z[i];
}

// conv weights OIHW fp32 -> packed-K MFMA A-fragment order (table-driven).
// WF[t][mt][lane] = W[oc = mt*16+Ai(l)][c = kg/9][tap = kg%9], kg = t*4+Ak(l);
// kg >= CIN*9 -> 0 (pad, CIN=3 tail only).
__global__ void prep_convw_frag(const float* __restrict__ src, double* __restrict__ dst,
                                const int* __restrict__ tabs,
                                int CIN, int nlayer, int wstride)
{
    int i = blockIdx.x * blockDim.x + threadIdx.x;
    int NS = (CIN * 9 + 3) / 4;
    int M  = NS * 256;
    if (i >= nlayer * M) return;
    int li  = i / M;
    int rem = i - li * M;
    int t   = rem >> 8;
    int j   = rem & 255;
    int mt  = j >> 6;
    int l   = j & 63;
    int kg  = t * 4 + tabs[T_AK + l];
    int oc  = mt * 16 + tabs[T_AI + l];
    int c   = kg / 9;
    int tap = kg - c * 9;
    dst[i] = (kg < CIN * 9) ? (double)src[li * wstride + (oc * CIN + c) * 9 + tap] : 0.0;
}

// bias fp32 -> C-fragment order fp64
__global__ void prep_bias_frag(const float* __restrict__ src, double* __restrict__ dst,
                               const int* __restrict__ tabs, int nlayer)
{
    int i = blockIdx.x * blockDim.x + threadIdx.x;
    if (i >= nlayer * 1024) return;
    int li  = i >> 10;
    int j   = i & 1023;
    int mtr = j >> 6;
    int l   = j & 63;
    int mt  = mtr >> 2, r = mtr & 3;
    dst[i] = (double)src[li * 64 + mt * 16 + tabs[T_DI + r * 64 + l]];
}

// last_w (441,64) -> A-fragment order WtA[kk][mt][lane] =
// W[tap = mt*16+Ai(l)][c = kk*4+Ak(l)] (tap>=441 -> 0); lbp padded bias.
__global__ void prep_lastwa(const float* __restrict__ lw, const float* __restrict__ lb,
                            const int* __restrict__ tabs,
                            double* __restrict__ wta, double* __restrict__ lbp)
{
    int i = blockIdx.x * blockDim.x + threadIdx.x;
    if (i < WTA_N) {
        int kk = i / (28 * 64);
        int rem = i - kk * (28 * 64);
        int mt = rem >> 6;
        int l  = rem & 63;
        int c  = kk * 4 + tabs[T_AK + l];
        int T  = mt * 16 + tabs[T_AI + l];
        wta[i] = (T < K2) ? (double)lw[T * 64 + c] : 0.0;
    }
    if (i < K2P) lbp[i] = (i < K2) ? (double)lb[i] : 0.0;
}

// wsum[c] = sum_T lw[T][c] (fp64, T-ascending); wsum[64] = sum_T lb[T]
__global__ void prep_wsum(const float* __restrict__ lw, const float* __restrict__ lb,
                          double* __restrict__ wsum)
{
    int c = threadIdx.x;
    if (c < 64) {
        double s = 0.0;
        for (int t = 0; t < K2; ++t) s += (double)lw[t * 64 + c];
        wsum[c] = s;
    }
    if (c == 64) {
        double s = 0.0;
        for (int t = 0; t < K2; ++t) s += (double)lb[t];
        wsum[64] = s;
    }
}

// ---------------------------------------------------------------------------
// conv3x3 as packed-K fp64 MFMA GEMM: D(64oc x 64pos) = WF(64 x CIN*9) * P.
// Channels in groups of 4: 36 taps = 9 exact K=4 steps (no pad for CIN=64).
// Depth-2 register prefetch: slot = t%3 (verified 44 us/disp; depth-3,
// OC-split, depth-4 ALL regressed — do not restructure). Grid 512, 2/CU.
// ---------------------------------------------------------------------------
template<int CIN, bool RELU, bool RESADD>
__global__ __launch_bounds__(256, 2)
void conv3x3_mfma(const double* __restrict__ in, const double* __restrict__ WF,
                  const double* __restrict__ BF, const int* __restrict__ tabs,
                  const double* __restrict__ res, double* __restrict__ out)
{
    constexpr int KT = CIN * 9;          // real K
    constexpr int NS = (KT + 3) / 4;     // K=4 steps (64ch: 144, 3ch: 7)
    constexpr int G  = (NS + 8) / 9;     // 4-channel groups

    const int bid = blockIdx.x;
    const int b   = bid & 7;
    const int y0  = bid >> 3;          // output row 0..63
    const int tid = threadIdx.x;
    const int w   = tid >> 6;
    const int l   = tid & 63;
    const int mi  = w >> 1, ni = w & 1;
    const int mt0 = mi * 2, nt0 = ni * 2;

    const int kB = tabs[T_BK + l];
    const int jB = tabs[T_BJ + l];

    // per-lane B offsets for the 9 steps of a 4-channel group.
    // kg = s*4 + kB in 0..35 -> c = kg/9, tap = kg%9. Pad slot (CIN=3 tail,
    // kg >= KT < 36) aliases addr 0 within the plane; weight there is 0.
    int offp[9];
#pragma unroll
    for (int s = 0; s < 9; ++s) {
        int kg  = s * 4 + kB;
        int off = 0;
        if (KT >= 36 || kg < KT) {
            int c   = kg / 9;
            int tap = kg - c * 9;
            int dy  = tap / 3, dx = tap - dy * 3;
            off = c * PS2 + dy * PS + dx;
        }
        offp[s] = off + jB + nt0 * 16;
    }

    const double* bbase = in + (size_t)b * CIN * PS2 + (size_t)y0 * PS;

    vdbl4 acc[2][2];
#pragma unroll
    for (int mt = 0; mt < 2; ++mt)
#pragma unroll
        for (int r = 0; r < 4; ++r) {
            double bv = BF[((mt0 + mt) * 4 + r) * 64 + l];
            acc[mt][0][r] = bv;
            acc[mt][1][r] = bv;
        }

    double aS[3][2], bS[3][2];
    auto ldA = [&](int t, int slot) {
        const double* p = WF + (size_t)t * 256 + l;
        aS[slot][0] = p[mt0 * 64];
        aS[slot][1] = p[(mt0 + 1) * 64];
    };
    auto ldB = [&](size_t cg, int s, int slot) {
        const double* p = bbase + cg + offp[s];
        bS[slot][0] = p[0];
        bS[slot][1] = p[16];
    };
    auto step = [&](int slot) {
        acc[0][0] = __builtin_amdgcn_mfma_f64_16x16x4f64(aS[slot][0], bS[slot][0], acc[0][0], 0, 0, 0);
        acc[0][1] = __builtin_amdgcn_mfma_f64_16x16x4f64(aS[slot][0], bS[slot][1], acc[0][1], 0, 0, 0);
        acc[1][0] = __builtin_amdgcn_mfma_f64_16x16x4f64(aS[slot][1], bS[slot][0], acc[1][0], 0, 0, 0);
        acc[1][1] = __builtin_amdgcn_mfma_f64_16x16x4f64(aS[slot][1], bS[slot][1], acc[1][1], 0, 0, 0);
    };

    // preload steps 0 and 1 (both in group 0)
    ldA(0, 0); ldB(0, 0, 0);
    ldA(1, 1); ldB(0, 1, 1);

    for (int g = 0; g < G; ++g) {
        const size_t cg = (size_t)g * 4 * PS2;
#pragma unroll
        for (int s = 0; s < 9; ++s) {
            const int t = g * 9 + s;                 // t%3 == s%3 (9 % 3 == 0)
            if (KT % 36 != 0 && t >= NS) break;      // CIN=3 tail only
            const int tp = t + 2;
            if (tp < NS) {
                const int    ps  = (s + 2 < 9) ? s + 2 : s - 7;
                const size_t pcg = (s + 2 < 9) ? cg : cg + 4 * PS2;
                ldA(tp, (s + 2) % 3);
                ldB(pcg, ps, (s + 2) % 3);
            }
            step(s % 3);
        }
    }

    // epilogue: D element (i,j) per (lane, reg) from probe tables
    int iD[4], jD[4];
#pragma unroll
    for (int r = 0; r < 4; ++r) {
        iD[r] = tabs[T_DI + r * 64 + l];
        jD[r] = tabs[T_DJ + r * 64 + l];
    }
#pragma unroll
    for (int mt = 0; mt < 2; ++mt)
#pragma unroll
        for (int nt = 0; nt < 2; ++nt)
#pragma unroll
            for (int r = 0; r < 4; ++r) {
                int oc = (mt0 + mt) * 16 + iD[r];
                int x  = (nt0 + nt) * 16 + jD[r];
                size_t idx = (size_t)(b * NF + oc) * PS2 + (size_t)(y0 + 1) * PS + x + 1;
                double val = acc[mt][nt][r];
                if (RELU)   val = fmax(val, 0.0);
                if (RESADD) val += res[idx];
                out[idx] = val;
            }
}

// ---------------------------------------------------------------------------
// 1x1 conv as fp64 MFMA GEMM, taps-as-M, TAP-GROUP blocks (r14 traffic fix,
// r15 4x grid: 1792 blocks) + FUSED tap-normalization (r16 verified:
// apply WRITE 58->1.5 MB): stores (float)(acc_f64 * inv_f64), inv from
// sums_kernel. Wave w owns mt = tg*4+w (16 tap rows) x 128 contiguous pos;
// A preloaded in 16 VGPRs; acc[4] indep MFMA chains; stores 16 taps x
// 256 B contiguous runs. No LDS.
// ---------------------------------------------------------------------------
__global__ __launch_bounds__(256, 2)
void lastconv_mfma(const double* __restrict__ hp, const double* __restrict__ wta,
                   const double* __restrict__ lbp, const int* __restrict__ tabs,
                   const double* __restrict__ inv_sums, float* __restrict__ kraw)
{
    const int bid = blockIdx.x;
    const int b   = bid / 224;
    const int rem = bid - b * 224;
    const int tg  = rem >> 5;          // 0..6
    const int pc  = rem & 31;          // 0..31
    const int tid = threadIdx.x;
    const int w   = tid >> 6;
    const int l   = tid & 63;
    const int mt  = tg * 4 + w;        // 0..27

    const int kB = tabs[T_BK + l];
    const int jB = tabs[T_BJ + l];
    int iD[4], jD[4];
#pragma unroll
    for (int r = 0; r < 4; ++r) {
        iD[r] = tabs[T_DI + r * 64 + l];
        jD[r] = tabs[T_DJ + r * 64 + l];
    }

    // preload A fragments for this mt: 16 doubles/lane
    double avs[16];
#pragma unroll
    for (int kk = 0; kk < 16; ++kk)
        avs[kk] = wta[((size_t)kk * 28 + mt) * 64 + l];

    // bias per accumulator register (same for all j-tiles)
    double bias[4];
#pragma unroll
    for (int r = 0; r < 4; ++r)
        bias[r] = lbp[mt * 16 + iD[r]];

    const double* hb = hp + (size_t)b * NF * PS2;
    float* kb = kraw + (size_t)b * K2 * SP;

    for (int q = 0; q < 2; ++q) {
        const int P0  = pc * 128 + q * 64;   // 64 positions = one spatial row
        const int row = P0 >> 6;
        const double* hrow = hb + (size_t)(row + 1) * PS + 1 + jB;

        // inv at this lane's 16 store positions (hidden under the K-loop)
        const double* isrow = inv_sums + (size_t)b * SP + P0;
        double isv[4][4];
#pragma unroll
        for (int j = 0; j < 4; ++j)
#pragma unroll
            for (int r = 0; r < 4; ++r)
                isv[j][r] = isrow[j * 16 + jD[r]];

        vdbl4 acc[4];
#pragma unroll
        for (int j = 0; j < 4; ++j)
#pragma unroll
            for (int r = 0; r < 4; ++r)
                acc[j][r] = bias[r];

        // prefetch B for kk=0 (c = kB)
        double bc[4], bn[4];
#pragma unroll
        for (int j = 0; j < 4; ++j)
            bc[j] = hrow[(size_t)kB * PS2 + j * 16];

        for (int kk = 0; kk < 16; ++kk) {
            if (kk < 15) {
                const double* np = hrow + (size_t)((kk + 1) * 4 + kB) * PS2;
#pragma unroll
                for (int j = 0; j < 4; ++j) bn[j] = np[j * 16];
            }
#pragma unroll
            for (int j = 0; j < 4; ++j)
                acc[j] = __builtin_amdgcn_mfma_f64_16x16x4f64(avs[kk], bc[j], acc[j], 0, 0, 0);
#pragma unroll
            for (int j = 0; j < 4; ++j) bc[j] = bn[j];
        }

        // epilogue: normalized stores, 16 taps x 4 x 64 B contiguous runs
#pragma unroll
        for (int r = 0; r < 4; ++r) {
            int T = mt * 16 + iD[r];
            if (T < K2) {
                float* p = kb + (size_t)T * SP + P0;
                p[jD[r]]      = (float)(acc[0][r] * isv[0][r]);
                p[16 + jD[r]] = (float)(acc[1][r] * isv[1][r]);
                p[32 + jD[r]] = (float)(acc[2][r] * isv[2][r]);
                p[48 + jD[r]] = (float)(acc[3][r] * isv[3][r]);
            }
        }
    }
}

// ---------------------------------------------------------------------------
// inv_sums[b][p] = 1 / (sum_c hp[c,p] * wsum[c] + wsum[64] + 1e-8)
// (exact refactoring of the tap-sum; fp64 reassociation ~1e-15 rel)
// ---------------------------------------------------------------------------
__global__ __launch_bounds__(256)
void sums_kernel(const double* __restrict__ hp, const double* __restrict__ wsum,
                 double* __restrict__ inv_sums)
{
    int i = blockIdx.x * 256 + threadIdx.x;   // 0..32767
    int b = i >> 12, p = i & 4095;
    int y = p >> 6, x = p & 63;
    const double* hb = hp + (size_t)b * NF * PS2 + (size_t)(y + 1) * PS + 1 + x;
    double s = wsum[64];
    for (int c = 0; c < 64; ++c) s += hb[(size_t)c * PS2] * wsum[c];
    inv_sums[b * SP + p] = 1.0 / (s + 1e-8);
}

// ---------------------------------------------------------------------------
// Apply normalized kernel (kout already normalized by lastconv) to
// reflect-padded 21x21 patches of x. r22: 4-WIDE UNROLLED gathers — r21
// counters showed VGPR=12 (compiler kept ~1 kout load in flight, 111
// serial ~500cy gathers, 880 GB/s latency-bound). 4 kn loads + 4 x-addr
// issued before use; fp32 accumulation order preserved (bit-identical).
// Block = (b, row): 64 px x 4 tap-chunks; 3KB LDS reduce; plain stores.
// ---------------------------------------------------------------------------
__global__ __launch_bounds__(256)
void apply_kernel(const float* __restrict__ x, const float* __restrict__ kout,
                  float* __restrict__ out)
{
    const int bid   = blockIdx.x;
    const int b     = bid >> 6;
    const int row   = bid & 63;
    const int tid   = threadIdx.x;
    const int chunk = tid >> 6;        // 0..3
    const int px    = tid & 63;
    const int p     = row * 64 + px;

    const float* xb = x + (size_t)b * 3 * 65536;
    const float* kb = kout + (size_t)b * K2 * SP + p;

    auto xaddr = [&](int tt) -> const float* {
        int ty = tt / 21, tx = tt - ty * 21;
        int gr = row * 4 + ty - 10;
        int gc = px * 4 + tx - 10;
        gr = gr < 0 ? -gr : (gr > 255 ? 510 - gr : gr);
        gc = gc < 0 ? -gc : (gc > 255 ? 510 - gc : gc);
        return xb + gr * 256 + gc;
    };

    float o0 = 0.f, o1 = 0.f, o2 = 0.f;
    const int t0 = chunk * 111;
    const int t1 = (t0 + 111 < K2) ? t0 + 111 : K2;

    int t = t0;
    for (; t + 4 <= t1; t += 4) {
        float kn0 = kb[(size_t)(t    ) * SP];
        float kn1 = kb[(size_t)(t + 1) * SP];
        float kn2 = kb[(size_t)(t + 2) * SP];
        float kn3 = kb[(size_t)(t + 3) * SP];
        const float* x0 = xaddr(t);
        const float* x1 = xaddr(t + 1);
        const float* x2 = xaddr(t + 2);
        const float* x3 = xaddr(t + 3);
        o0 = fmaf(x0[0], kn0, o0); o1 = fmaf(x0[65536], kn0, o1); o2 = fmaf(x0[131072], kn0, o2);
        o0 = fmaf(x1[0], kn1, o0); o1 = fmaf(x1[65536], kn1, o1); o2 = fmaf(x1[131072], kn1, o2);
        o0 = fmaf(x2[0], kn2, o0); o1 = fmaf(x2[65536], kn2, o1); o2 = fmaf(x2[131072], kn2, o2);
        o0 = fmaf(x3[0], kn3, o0); o1 = fmaf(x3[65536], kn3, o1); o2 = fmaf(x3[131072], kn3, o2);
    }
    for (; t < t1; ++t) {
        float kn = kb[(size_t)t * SP];
        const float* xp = xaddr(t);
        o0 = fmaf(xp[0],      kn, o0);
        o1 = fmaf(xp[65536],  kn, o1);
        o2 = fmaf(xp[131072], kn, o2);
    }

    __shared__ float red[3][4][64];
    if (chunk > 0) {
        red[0][chunk][px] = o0;
        red[1][chunk][px] = o1;
        red[2][chunk][px] = o2;
    }
    __syncthreads();
    if (chunk == 0) {
        o0 += red[0][1][px] + red[0][2][px] + red[0][3][px];
        o1 += red[1][1][px] + red[1][2][px] + red[1][3][px];
        o2 += red[2][1][px] + red[2][2][px] + red[2][3][px];
        out[(b * 3 + 0) * SP + p] = o0;
        out[(b * 3 + 1) * SP + p] = o1;
        out[(b * 3 + 2) * SP + p] = o2;
    }
}

// ---------------------------------------------------------------------------
extern "C" void kernel_launch(void* const* d_in, const int* in_sizes, int n_in,
                              void* d_out, int out_size, void* d_ws, size_t ws_size,
                              hipStream_t stream)
{
    (void)in_sizes; (void)n_in; (void)out_size; (void)ws_size;

    const float* x = (const float*)d_in[0];
    const float* z = (const float*)d_in[1];

    float* out  = (float*)d_out;                 // (8,3,64,64)
    float* kout = (float*)d_out + NB * 3 * SP;   // (8,441,64,64) normalized

    // ws layout (doubles)
    double* wd    = (double*)d_ws;
    double* probe = wd;                      // 512 (D1, D2)
    int*    tabs  = (int*)(wd + 512);        // 1024 ints (=512 doubles)
    double* wf0   = wd + 1024;               // 1792
    double* wf1   = wf0 + WF_C0;             // 8*36864
    double* wf2   = wf1 + 8 * WF_RES;        // 8*36864
    double* bf0   = wf2 + 8 * WF_RES;        // 1024
    double* bf1   = bf0 + 1024;              // 8*1024
    double* bf2   = bf1 + 8 * 1024;          // 8*1024
    double* wta   = bf2 + 8 * 1024;          // 28672
    double* lbp   = wta + WTA_N;             // 448
    double* wsum  = lbp + K2P;               // 72
    double* zp    = wsum + 72;               // 8*3*66*66
    double* hp    = zp + NB * 3 * PS2;       // 8*64*66*66 = 17.8 MB
    double* tp    = hp + NB * NF * PS2;      // 17.8 MB
    double* sums  = tp;                      // aliases tp (free after conv chain)

    // zero padded buffers (borders must be 0; interiors get overwritten)
    hipMemsetAsync(zp, 0, (size_t)NB * 3 * PS2 * sizeof(double), stream);
    hipMemsetAsync(hp, 0, (size_t)NB * NF * PS2 * sizeof(double), stream);
    hipMemsetAsync(tp, 0, (size_t)NB * NF * PS2 * sizeof(double), stream);

    // layout probe, then table-driven prep
    probe_mfma<<<1, 64, 0, stream>>>(probe);
    decode_probe<<<1, 256, 0, stream>>>(probe, tabs);

    prep_zpad<<<(NB * 3 * SP + 255) / 256, 256, 0, stream>>>(z, zp);
    prep_convw_frag<<<(WF_C0 + 255) / 256, 256, 0, stream>>>(
        (const float*)d_in[2], wf0, tabs, 3, 1, 0);
    prep_convw_frag<<<(8 * WF_RES + 255) / 256, 256, 0, stream>>>(
        (const float*)d_in[4], wf1, tabs, 64, 8, RES_WSTRIDE);
    prep_convw_frag<<<(8 * WF_RES + 255) / 256, 256, 0, stream>>>(
        (const float*)d_in[6], wf2, tabs, 64, 8, RES_WSTRIDE);
    prep_bias_frag<<<(1024 + 255) / 256, 256, 0, stream>>>(
        (const float*)d_in[3], bf0, tabs, 1);
    prep_bias_frag<<<(8 * 1024 + 255) / 256, 256, 0, stream>>>(
        (const float*)d_in[5], bf1, tabs, 8);
    prep_bias_frag<<<(8 * 1024 + 255) / 256, 256, 0, stream>>>(
        (const float*)d_in[7], bf2, tabs, 8);
    prep_lastwa<<<(WTA_N + 255) / 256, 256, 0, stream>>>(
        (const float*)d_in[8], (const float*)d_in[9], tabs, wta, lbp);
    prep_wsum<<<1, 128, 0, stream>>>(
        (const float*)d_in[8], (const float*)d_in[9], wsum);

    conv3x3_mfma<3,  false, false><<<512, 256, 0, stream>>>(zp, wf0, bf0, tabs, nullptr, hp);
    for (int i = 0; i < 8; ++i) {
        conv3x3_mfma<64, true,  false><<<512, 256, 0, stream>>>(
            hp, wf1 + i * WF_RES, bf1 + i * 1024, tabs, nullptr, tp);
        conv3x3_mfma<64, false, true ><<<512, 256, 0, stream>>>(
            tp, wf2 + i * WF_RES, bf2 + i * 1024, tabs, hp, hp);
    }
    sums_kernel<<<128, 256, 0, stream>>>(hp, wsum, sums);
    lastconv_mfma<<<1792, 256, 0, stream>>>(hp, wta, lbp, tabs, sums, kout);
    apply_kernel<<<512, 256, 0, stream>>>(x, kout, out);
}

// Round 19
// 891.399 us; speedup vs baseline: 1.0408x; 1.0020x over previous
//
#include <hip/hip_runtime.h>

// DegModel: kernel-prediction net (17x conv3x3 + 1x1 conv to 441 taps) +
// tap-normalized spatially-varying 21x21 downsample (stride 4, reflect pad).
//
// fp64 conv chain (1/tap-sum amplification: fp32 chain fails 1280 > 1177;
// fp64 passes at 576). Round 23:
//  - conv3x3: depth-2 packed-K fp64 MFMA GEMM — FINAL (44 us/disp; depth-3,
//    OC-split, depth-4 all regressed; do not restructure).
//  - lastconv: kk-prefetch DEPTH-2 (bc/bn/bn2 rotation). r22 counters:
//    MfmaUtil 44%, Occ 24%, mem traffic ideal -> per-wave B latency
//    (depth-1 = 256cy lead vs ~600cy L2/L3). Tiny unrolled loop + A in
//    registers => depth bump is ~8 VGPR, no branches (unlike conv's
//    failed restructures). MFMA order unchanged, bit-identical.
//  - apply: 4-wide unrolled gathers (r22 verified: dropped out of top-5).
//  - sums_kernel stores inv = 1/(s+1e-8); apply read-only on kout.
// On-device layout probe (r8 lesson: assumed f64 MFMA maps were wrong).

#define NB 8        // batch
#define NF 64       // features
#define SP 4096     // 64*64 spatial
#define PS 66       // padded spatial dim
#define PS2 4356    // 66*66
#define K2 441      // 21*21 taps
#define K2P 448     // padded taps
#define RES_WSTRIDE (64*64*9)
// packed-K fragment sizes: NS(CIN) = ceil(CIN*9/4) steps, 4 mt-tiles, 64 lanes
#define WF_RES 36864           // 144 steps * 256
#define WF_C0  1792            // 7 steps * 256
#define WTA_N  28672           // 16kk * 28mt * 64

typedef double vdbl4 __attribute__((ext_vector_type(4)));

// table offsets (ints) within the tabs block
#define T_AI 0      // [64]  A: lane -> i
#define T_AK 64     // [64]  A: lane -> k
#define T_BK 128    // [64]  B: lane -> k
#define T_BJ 192    // [64]  B: lane -> j
#define T_DI 256    // [256] D: r*64+l -> i
#define T_DJ 512    // [256] D: r*64+l -> j

// ---------------------------------------------------------------------------
// layout probe: one wave. D1[l,r] = rowsumA(i(l,r)), D2[l,r] = colsumB(j(l,r))
__global__ void probe_mfma(double* __restrict__ probe)
{
    int l = threadIdx.x;
    vdbl4 z = {0.0, 0.0, 0.0, 0.0};
    vdbl4 r1 = __builtin_amdgcn_mfma_f64_16x16x4f64((double)l, 1.0, z, 0, 0, 0);
    vdbl4 r2 = __builtin_amdgcn_mfma_f64_16x16x4f64(1.0, (double)l, z, 0, 0, 0);
#pragma unroll
    for (int r = 0; r < 4; ++r) {
        probe[r * 64 + l]       = r1[r];
        probe[256 + r * 64 + l] = r2[r];
    }
}

__global__ void decode_probe(const double* __restrict__ probe, int* __restrict__ tabs)
{
    int t = threadIdx.x;                 // 0..255
    const double* d1 = probe;
    const double* d2 = probe + 256;
    // lane=i+16k => rowsum=96+4i (mod4==0); lane=4i+k => 6+16i (mod4==2)
    bool fA = ((((int)d1[0]) & 3) == 0);
    bool fB = ((((int)d2[0]) & 3) == 0);
    int v1 = (int)d1[t], v2 = (int)d2[t];
    tabs[T_DI + t] = fA ? (v1 - 96) >> 2 : (v1 - 6) >> 4;
    tabs[T_DJ + t] = fB ? (v2 - 96) >> 2 : (v2 - 6) >> 4;
    if (t < 64) {
        tabs[T_AI + t] = fA ? (t & 15) : (t >> 2);
        tabs[T_AK + t] = fA ? (t >> 4) : (t & 3);
        tabs[T_BK + t] = fB ? (t >> 4) : (t & 3);
        tabs[T_BJ + t] = fB ? (t & 15) : (t >> 2);
    }
}

// ---------------------------------------------------------------------------
// z (8,3,64,64) fp32 -> zp (8,3,66,66) fp64 interior (borders pre-zeroed)
__global__ void prep_zpad(const float* __restrict__ z, double* __restrict__ zp)
{
    int i = blockIdx.x * blockDim.x + threadIdx.x;
    if (i >= NB * 3 * SP) return;
    int bc = i >> 12, p = i & 4095, y = p >> 6, x = p & 63;
    zp[(size_t)(bc * PS + y + 1) * PS + x + 1] = (double)z[i];
}

// conv weights OIHW fp32 -> packed-K MFMA A-fragment order (table-driven).
// WF[t][mt][lane] = W[oc = mt*16+Ai(l)][c = kg/9][tap = kg%9], kg = t*4+Ak(l);
// kg >= CIN*9 -> 0 (pad, CIN=3 tail only).
__global__ void prep_convw_frag(const float* __restrict__ src, double* __restrict__ dst,
                                const int* __restrict__ tabs,
                                int CIN, int nlayer, int wstride)
{
    int i = blockIdx.x * blockDim.x + threadIdx.x;
    int NS = (CIN * 9 + 3) / 4;
    int M  = NS * 256;
    if (i >= nlayer * M) return;
    int li  = i / M;
    int rem = i - li * M;
    int t   = rem >> 8;
    int j   = rem & 255;
    int mt  = j >> 6;
    int l   = j & 63;
    int kg  = t * 4 + tabs[T_AK + l];
    int oc  = mt * 16 + tabs[T_AI + l];
    int c   = kg / 9;
    int tap = kg - c * 9;
    dst[i] = (kg < CIN * 9) ? (double)src[li * wstride + (oc * CIN + c) * 9 + tap] : 0.0;
}

// bias fp32 -> C-fragment order fp64
__global__ void prep_bias_frag(const float* __restrict__ src, double* __restrict__ dst,
                               const int* __restrict__ tabs, int nlayer)
{
    int i = blockIdx.x * blockDim.x + threadIdx.x;
    if (i >= nlayer * 1024) return;
    int li  = i >> 10;
    int j   = i & 1023;
    int mtr = j >> 6;
    int l   = j & 63;
    int mt  = mtr >> 2, r = mtr & 3;
    dst[i] = (double)src[li * 64 + mt * 16 + tabs[T_DI + r * 64 + l]];
}

// last_w (441,64) -> A-fragment order WtA[kk][mt][lane] =
// W[tap = mt*16+Ai(l)][c = kk*4+Ak(l)] (tap>=441 -> 0); lbp padded bias.
__global__ void prep_lastwa(const float* __restrict__ lw, const float* __restrict__ lb,
                            const int* __restrict__ tabs,
                            double* __restrict__ wta, double* __restrict__ lbp)
{
    int i = blockIdx.x * blockDim.x + threadIdx.x;
    if (i < WTA_N) {
        int kk = i / (28 * 64);
        int rem = i - kk * (28 * 64);
        int mt = rem >> 6;
        int l  = rem & 63;
        int c  = kk * 4 + tabs[T_AK + l];
        int T  = mt * 16 + tabs[T_AI + l];
        wta[i] = (T < K2) ? (double)lw[T * 64 + c] : 0.0;
    }
    if (i < K2P) lbp[i] = (i < K2) ? (double)lb[i] : 0.0;
}

// wsum[c] = sum_T lw[T][c] (fp64, T-ascending); wsum[64] = sum_T lb[T]
__global__ void prep_wsum(const float* __restrict__ lw, const float* __restrict__ lb,
                          double* __restrict__ wsum)
{
    int c = threadIdx.x;
    if (c < 64) {
        double s = 0.0;
        for (int t = 0; t < K2; ++t) s += (double)lw[t * 64 + c];
        wsum[c] = s;
    }
    if (c == 64) {
        double s = 0.0;
        for (int t = 0; t < K2; ++t) s += (double)lb[t];
        wsum[64] = s;
    }
}

// ---------------------------------------------------------------------------
// conv3x3 as packed-K fp64 MFMA GEMM: D(64oc x 64pos) = WF(64 x CIN*9) * P.
// Channels in groups of 4: 36 taps = 9 exact K=4 steps (no pad for CIN=64).
// Depth-2 register prefetch: slot = t%3 (verified 44 us/disp; depth-3,
// OC-split, depth-4 ALL regressed — do not restructure). Grid 512, 2/CU.
// ---------------------------------------------------------------------------
template<int CIN, bool RELU, bool RESADD>
__global__ __launch_bounds__(256, 2)
void conv3x3_mfma(const double* __restrict__ in, const double* __restrict__ WF,
                  const double* __restrict__ BF, const int* __restrict__ tabs,
                  const double* __restrict__ res, double* __restrict__ out)
{
    constexpr int KT = CIN * 9;          // real K
    constexpr int NS = (KT + 3) / 4;     // K=4 steps (64ch: 144, 3ch: 7)
    constexpr int G  = (NS + 8) / 9;     // 4-channel groups

    const int bid = blockIdx.x;
    const int b   = bid & 7;
    const int y0  = bid >> 3;          // output row 0..63
    const int tid = threadIdx.x;
    const int w   = tid >> 6;
    const int l   = tid & 63;
    const int mi  = w >> 1, ni = w & 1;
    const int mt0 = mi * 2, nt0 = ni * 2;

    const int kB = tabs[T_BK + l];
    const int jB = tabs[T_BJ + l];

    // per-lane B offsets for the 9 steps of a 4-channel group.
    // kg = s*4 + kB in 0..35 -> c = kg/9, tap = kg%9. Pad slot (CIN=3 tail,
    // kg >= KT < 36) aliases addr 0 within the plane; weight there is 0.
    int offp[9];
#pragma unroll
    for (int s = 0; s < 9; ++s) {
        int kg  = s * 4 + kB;
        int off = 0;
        if (KT >= 36 || kg < KT) {
            int c   = kg / 9;
            int tap = kg - c * 9;
            int dy  = tap / 3, dx = tap - dy * 3;
            off = c * PS2 + dy * PS + dx;
        }
        offp[s] = off + jB + nt0 * 16;
    }

    const double* bbase = in + (size_t)b * CIN * PS2 + (size_t)y0 * PS;

    vdbl4 acc[2][2];
#pragma unroll
    for (int mt = 0; mt < 2; ++mt)
#pragma unroll
        for (int r = 0; r < 4; ++r) {
            double bv = BF[((mt0 + mt) * 4 + r) * 64 + l];
            acc[mt][0][r] = bv;
            acc[mt][1][r] = bv;
        }

    double aS[3][2], bS[3][2];
    auto ldA = [&](int t, int slot) {
        const double* p = WF + (size_t)t * 256 + l;
        aS[slot][0] = p[mt0 * 64];
        aS[slot][1] = p[(mt0 + 1) * 64];
    };
    auto ldB = [&](size_t cg, int s, int slot) {
        const double* p = bbase + cg + offp[s];
        bS[slot][0] = p[0];
        bS[slot][1] = p[16];
    };
    auto step = [&](int slot) {
        acc[0][0] = __builtin_amdgcn_mfma_f64_16x16x4f64(aS[slot][0], bS[slot][0], acc[0][0], 0, 0, 0);
        acc[0][1] = __builtin_amdgcn_mfma_f64_16x16x4f64(aS[slot][0], bS[slot][1], acc[0][1], 0, 0, 0);
        acc[1][0] = __builtin_amdgcn_mfma_f64_16x16x4f64(aS[slot][1], bS[slot][0], acc[1][0], 0, 0, 0);
        acc[1][1] = __builtin_amdgcn_mfma_f64_16x16x4f64(aS[slot][1], bS[slot][1], acc[1][1], 0, 0, 0);
    };

    // preload steps 0 and 1 (both in group 0)
    ldA(0, 0); ldB(0, 0, 0);
    ldA(1, 1); ldB(0, 1, 1);

    for (int g = 0; g < G; ++g) {
        const size_t cg = (size_t)g * 4 * PS2;
#pragma unroll
        for (int s = 0; s < 9; ++s) {
            const int t = g * 9 + s;                 // t%3 == s%3 (9 % 3 == 0)
            if (KT % 36 != 0 && t >= NS) break;      // CIN=3 tail only
            const int tp = t + 2;
            if (tp < NS) {
                const int    ps  = (s + 2 < 9) ? s + 2 : s - 7;
                const size_t pcg = (s + 2 < 9) ? cg : cg + 4 * PS2;
                ldA(tp, (s + 2) % 3);
                ldB(pcg, ps, (s + 2) % 3);
            }
            step(s % 3);
        }
    }

    // epilogue: D element (i,j) per (lane, reg) from probe tables
    int iD[4], jD[4];
#pragma unroll
    for (int r = 0; r < 4; ++r) {
        iD[r] = tabs[T_DI + r * 64 + l];
        jD[r] = tabs[T_DJ + r * 64 + l];
    }
#pragma unroll
    for (int mt = 0; mt < 2; ++mt)
#pragma unroll
        for (int nt = 0; nt < 2; ++nt)
#pragma unroll
            for (int r = 0; r < 4; ++r) {
                int oc = (mt0 + mt) * 16 + iD[r];
                int x  = (nt0 + nt) * 16 + jD[r];
                size_t idx = (size_t)(b * NF + oc) * PS2 + (size_t)(y0 + 1) * PS + x + 1;
                double val = acc[mt][nt][r];
                if (RELU)   val = fmax(val, 0.0);
                if (RESADD) val += res[idx];
                out[idx] = val;
            }
}

// ---------------------------------------------------------------------------
// 1x1 conv as fp64 MFMA GEMM, taps-as-M, TAP-GROUP blocks (r14 traffic fix,
// r15 4x grid: 1792 blocks) + FUSED tap-normalization. r23: kk-prefetch
// depth-2 (bc/bn/bn2): r22 counters MfmaUtil 44%, traffic ideal -> B
// latency (depth-1 = 256cy lead < ~600cy L2/L3). Loads for kk+2 issued
// before kk's MFMAs; MFMA order unchanged (bit-identical). Wave w owns
// mt = tg*4+w (16 tap rows) x 128 pos; A in 16 VGPRs; stores 16 taps x
// 256 B contiguous runs. No LDS.
// ---------------------------------------------------------------------------
__global__ __launch_bounds__(256, 2)
void lastconv_mfma(const double* __restrict__ hp, const double* __restrict__ wta,
                   const double* __restrict__ lbp, const int* __restrict__ tabs,
                   const double* __restrict__ inv_sums, float* __restrict__ kraw)
{
    const int bid = blockIdx.x;
    const int b   = bid / 224;
    const int rem = bid - b * 224;
    const int tg  = rem >> 5;          // 0..6
    const int pc  = rem & 31;          // 0..31
    const int tid = threadIdx.x;
    const int w   = tid >> 6;
    const int l   = tid & 63;
    const int mt  = tg * 4 + w;        // 0..27

    const int kB = tabs[T_BK + l];
    const int jB = tabs[T_BJ + l];
    int iD[4], jD[4];
#pragma unroll
    for (int r = 0; r < 4; ++r) {
        iD[r] = tabs[T_DI + r * 64 + l];
        jD[r] = tabs[T_DJ + r * 64 + l];
    }

    // preload A fragments for this mt: 16 doubles/lane
    double avs[16];
#pragma unroll
    for (int kk = 0; kk < 16; ++kk)
        avs[kk] = wta[((size_t)kk * 28 + mt) * 64 + l];

    // bias per accumulator register (same for all j-tiles)
    double bias[4];
#pragma unroll
    for (int r = 0; r < 4; ++r)
        bias[r] = lbp[mt * 16 + iD[r]];

    const double* hb = hp + (size_t)b * NF * PS2;
    float* kb = kraw + (size_t)b * K2 * SP;

    for (int q = 0; q < 2; ++q) {
        const int P0  = pc * 128 + q * 64;   // 64 positions = one spatial row
        const int row = P0 >> 6;
        const double* hrow = hb + (size_t)(row + 1) * PS + 1 + jB;

        // inv at this lane's 16 store positions (hidden under the K-loop)
        const double* isrow = inv_sums + (size_t)b * SP + P0;
        double isv[4][4];
#pragma unroll
        for (int j = 0; j < 4; ++j)
#pragma unroll
            for (int r = 0; r < 4; ++r)
                isv[j][r] = isrow[j * 16 + jD[r]];

        vdbl4 acc[4];
#pragma unroll
        for (int j = 0; j < 4; ++j)
#pragma unroll
            for (int r = 0; r < 4; ++r)
                acc[j][r] = bias[r];

        // depth-2 B prefetch: bc = kk, bn = kk+1, bn2 = kk+2 in flight
        double bc[4], bn[4], bn2[4];
#pragma unroll
        for (int j = 0; j < 4; ++j)
            bc[j] = hrow[(size_t)kB * PS2 + j * 16];
#pragma unroll
        for (int j = 0; j < 4; ++j)
            bn[j] = hrow[(size_t)(4 + kB) * PS2 + j * 16];

        for (int kk = 0; kk < 16; ++kk) {
            if (kk < 14) {
                const double* np = hrow + (size_t)((kk + 2) * 4 + kB) * PS2;
#pragma unroll
                for (int j = 0; j < 4; ++j) bn2[j] = np[j * 16];
            }
#pragma unroll
            for (int j = 0; j < 4; ++j)
                acc[j] = __builtin_amdgcn_mfma_f64_16x16x4f64(avs[kk], bc[j], acc[j], 0, 0, 0);
#pragma unroll
            for (int j = 0; j < 4; ++j) { bc[j] = bn[j]; bn[j] = bn2[j]; }
        }

        // epilogue: normalized stores, 16 taps x 4 x 64 B contiguous runs
#pragma unroll
        for (int r = 0; r < 4; ++r) {
            int T = mt * 16 + iD[r];
            if (T < K2) {
                float* p = kb + (size_t)T * SP + P0;
                p[jD[r]]      = (float)(acc[0][r] * isv[0][r]);
                p[16 + jD[r]] = (float)(acc[1][r] * isv[1][r]);
                p[32 + jD[r]] = (float)(acc[2][r] * isv[2][r]);
                p[48 + jD[r]] = (float)(acc[3][r] * isv[3][r]);
            }
        }
    }
}

// ---------------------------------------------------------------------------
// inv_sums[b][p] = 1 / (sum_c hp[c,p] * wsum[c] + wsum[64] + 1e-8)
// (exact refactoring of the tap-sum; fp64 reassociation ~1e-15 rel)
// ---------------------------------------------------------------------------
__global__ __launch_bounds__(256)
void sums_kernel(const double* __restrict__ hp, const double* __restrict__ wsum,
                 double* __restrict__ inv_sums)
{
    int i = blockIdx.x * 256 + threadIdx.x;   // 0..32767
    int b = i >> 12, p = i & 4095;
    int y = p >> 6, x = p & 63;
    const double* hb = hp + (size_t)b * NF * PS2 + (size_t)(y + 1) * PS + 1 + x;
    double s = wsum[64];
    for (int c = 0; c < 64; ++c) s += hb[(size_t)c * PS2] * wsum[c];
    inv_sums[b * SP + p] = 1.0 / (s + 1e-8);
}

// ---------------------------------------------------------------------------
// Apply normalized kernel (kout already normalized by lastconv) to
// reflect-padded 21x21 patches of x. 4-wide unrolled gathers (r22
// verified). Block = (b, row): 64 px x 4 tap-chunks; 3KB LDS reduce;
// plain stores.
// ---------------------------------------------------------------------------
__global__ __launch_bounds__(256)
void apply_kernel(const float* __restrict__ x, const float* __restrict__ kout,
                  float* __restrict__ out)
{
    const int bid   = blockIdx.x;
    const int b     = bid >> 6;
    const int row   = bid & 63;
    const int tid   = threadIdx.x;
    const int chunk = tid >> 6;        // 0..3
    const int px    = tid & 63;
    const int p     = row * 64 + px;

    const float* xb = x + (size_t)b * 3 * 65536;
    const float* kb = kout + (size_t)b * K2 * SP + p;

    auto xaddr = [&](int tt) -> const float* {
        int ty = tt / 21, tx = tt - ty * 21;
        int gr = row * 4 + ty - 10;
        int gc = px * 4 + tx - 10;
        gr = gr < 0 ? -gr : (gr > 255 ? 510 - gr : gr);
        gc = gc < 0 ? -gc : (gc > 255 ? 510 - gc : gc);
        return xb + gr * 256 + gc;
    };

    float o0 = 0.f, o1 = 0.f, o2 = 0.f;
    const int t0 = chunk * 111;
    const int t1 = (t0 + 111 < K2) ? t0 + 111 : K2;

    int t = t0;
    for (; t + 4 <= t1; t += 4) {
        float kn0 = kb[(size_t)(t    ) * SP];
        float kn1 = kb[(size_t)(t + 1) * SP];
        float kn2 = kb[(size_t)(t + 2) * SP];
        float kn3 = kb[(size_t)(t + 3) * SP];
        const float* x0 = xaddr(t);
        const float* x1 = xaddr(t + 1);
        const float* x2 = xaddr(t + 2);
        const float* x3 = xaddr(t + 3);
        o0 = fmaf(x0[0], kn0, o0); o1 = fmaf(x0[65536], kn0, o1); o2 = fmaf(x0[131072], kn0, o2);
        o0 = fmaf(x1[0], kn1, o0); o1 = fmaf(x1[65536], kn1, o1); o2 = fmaf(x1[131072], kn1, o2);
        o0 = fmaf(x2[0], kn2, o0); o1 = fmaf(x2[65536], kn2, o1); o2 = fmaf(x2[131072], kn2, o2);
        o0 = fmaf(x3[0], kn3, o0); o1 = fmaf(x3[65536], kn3, o1); o2 = fmaf(x3[131072], kn3, o2);
    }
    for (; t < t1; ++t) {
        float kn = kb[(size_t)t * SP];
        const float* xp = xaddr(t);
        o0 = fmaf(xp[0],      kn, o0);
        o1 = fmaf(xp[65536],  kn, o1);
        o2 = fmaf(xp[131072], kn, o2);
    }

    __shared__ float red[3][4][64];
    if (chunk > 0) {
        red[0][chunk][px] = o0;
        red[1][chunk][px] = o1;
        red[2][chunk][px] = o2;
    }
    __syncthreads();
    if (chunk == 0) {
        o0 += red[0][1][px] + red[0][2][px] + red[0][3][px];
        o1 += red[1][1][px] + red[1][2][px] + red[1][3][px];
        o2 += red[2][1][px] + red[2][2][px] + red[2][3][px];
        out[(b * 3 + 0) * SP + p] = o0;
        out[(b * 3 + 1) * SP + p] = o1;
        out[(b * 3 + 2) * SP + p] = o2;
    }
}

// ---------------------------------------------------------------------------
extern "C" void kernel_launch(void* const* d_in, const int* in_sizes, int n_in,
                              void* d_out, int out_size, void* d_ws, size_t ws_size,
                              hipStream_t stream)
{
    (void)in_sizes; (void)n_in; (void)out_size; (void)ws_size;

    const float* x = (const float*)d_in[0];
    const float* z = (const float*)d_in[1];

    float* out  = (float*)d_out;                 // (8,3,64,64)
    float* kout = (float*)d_out + NB * 3 * SP;   // (8,441,64,64) normalized

    // ws layout (doubles)
    double* wd    = (double*)d_ws;
    double* probe = wd;                      // 512 (D1, D2)
    int*    tabs  = (int*)(wd + 512);        // 1024 ints (=512 doubles)
    double* wf0   = wd + 1024;               // 1792
    double* wf1   = wf0 + WF_C0;             // 8*36864
    double* wf2   = wf1 + 8 * WF_RES;        // 8*36864
    double* bf0   = wf2 + 8 * WF_RES;        // 1024
    double* bf1   = bf0 + 1024;              // 8*1024
    double* bf2   = bf1 + 8 * 1024;          // 8*1024
    double* wta   = bf2 + 8 * 1024;          // 28672
    double* lbp   = wta + WTA_N;             // 448
    double* wsum  = lbp + K2P;               // 72
    double* zp    = wsum + 72;               // 8*3*66*66
    double* hp    = zp + NB * 3 * PS2;       // 8*64*66*66 = 17.8 MB
    double* tp    = hp + NB * NF * PS2;      // 17.8 MB
    double* sums  = tp;                      // aliases tp (free after conv chain)

    // zero padded buffers (borders must be 0; interiors get overwritten)
    hipMemsetAsync(zp, 0, (size_t)NB * 3 * PS2 * sizeof(double), stream);
    hipMemsetAsync(hp, 0, (size_t)NB * NF * PS2 * sizeof(double), stream);
    hipMemsetAsync(tp, 0, (size_t)NB * NF * PS2 * sizeof(double), stream);

    // layout probe, then table-driven prep
    probe_mfma<<<1, 64, 0, stream>>>(probe);
    decode_probe<<<1, 256, 0, stream>>>(probe, tabs);

    prep_zpad<<<(NB * 3 * SP + 255) / 256, 256, 0, stream>>>(z, zp);
    prep_convw_frag<<<(WF_C0 + 255) / 256, 256, 0, stream>>>(
        (const float*)d_in[2], wf0, tabs, 3, 1, 0);
    prep_convw_frag<<<(8 * WF_RES + 255) / 256, 256, 0, stream>>>(
        (const float*)d_in[4], wf1, tabs, 64, 8, RES_WSTRIDE);
    prep_convw_frag<<<(8 * WF_RES + 255) / 256, 256, 0, stream>>>(
        (const float*)d_in[6], wf2, tabs, 64, 8, RES_WSTRIDE);
    prep_bias_frag<<<(1024 + 255) / 256, 256, 0, stream>>>(
        (const float*)d_in[3], bf0, tabs, 1);
    prep_bias_frag<<<(8 * 1024 + 255) / 256, 256, 0, stream>>>(
        (const float*)d_in[5], bf1, tabs, 8);
    prep_bias_frag<<<(8 * 1024 + 255) / 256, 256, 0, stream>>>(
        (const float*)d_in[7], bf2, tabs, 8);
    prep_lastwa<<<(WTA_N + 255) / 256, 256, 0, stream>>>(
        (const float*)d_in[8], (const float*)d_in[9], tabs, wta, lbp);
    prep_wsum<<<1, 128, 0, stream>>>(
        (const float*)d_in[8], (const float*)d_in[9], wsum);

    conv3x3_mfma<3,  false, false><<<512, 256, 0, stream>>>(zp, wf0, bf0, tabs, nullptr, hp);
    for (int i = 0; i < 8; ++i) {
        conv3x3_mfma<64, true,  false><<<512, 256, 0, stream>>>(
            hp, wf1 + i * WF_RES, bf1 + i * 1024, tabs, nullptr, tp);
        conv3x3_mfma<64, false, true ><<<512, 256, 0, stream>>>(
            tp, wf2 + i * WF_RES, bf2 + i * 1024, tabs, hp, hp);
    }
    sums_kernel<<<128, 256, 0, stream>>>(hp, wsum, sums);
    lastconv_mfma<<<1792, 256, 0, stream>>>(hp, wta, lbp, tabs, sums, kout);
    apply_kernel<<<512, 256, 0, stream>>>(x, kout, out);
}